// Round 20
// baseline (108.709 us; speedup 1.0000x reference)
//
#include <hip/hip_runtime.h>
#include <hip/hip_bf16.h>
#include <math.h>

typedef short bf16x8 __attribute__((ext_vector_type(8)));
typedef float f32x4 __attribute__((ext_vector_type(4)));

#define T_SEQ 2048
#define C_DIM 1024
#define H_HEADS 16
#define D_HEAD 64
#define BT 4096          // B*T
#define C3 3072
#define BH 32            // B*H

static __device__ inline unsigned short bf_bits(float f) {
    __hip_bfloat16 h = __float2bfloat16(f);
    unsigned short u;
    __builtin_memcpy(&u, &h, 2);
    return u;
}

// packed f32x2 -> bf16x2 (RNE), single instruction
static __device__ inline unsigned int cvtpk(float lo, float hi) {
    unsigned int r;
    asm("v_cvt_pk_bf16_f32 %0, %1, %2" : "=v"(r) : "v"(lo), "v"(hi));
    return r;
}

__device__ __forceinline__ void gload16(const void* g, void* l) {
    __builtin_amdgcn_global_load_lds(
        (const __attribute__((address_space(1))) void*)g,
        (__attribute__((address_space(3))) void*)l, 16, 0, 0);
}

// LDS XOR swizzle (element units, 8-elem granule): spreads rows across bank quads
__device__ __forceinline__ int swz(int r) {
    return ((((r & 3) ^ ((r >> 3) & 3)) | (((r >> 3) & 1) << 2)) << 3);
}

// ---------------- fused prep: casts (x, W_attn, W_proj) + RoPE cos/sin table ----------------
__global__ void prep_kernel(const float* __restrict__ x,
                            const float* __restrict__ Wa,
                            const float* __restrict__ Wp,
                            const float* __restrict__ freqs,
                            __hip_bfloat16* __restrict__ xb,
                            __hip_bfloat16* __restrict__ Wab,
                            __hip_bfloat16* __restrict__ Wpb,
                            float2* __restrict__ tab) {
    const int bidx = blockIdx.x, tid = threadIdx.x;
    if (bidx < 8192) {
        const float* src;
        __hip_bfloat16* dst;
        int i;
        if (bidx < 4096)      { src = x;  dst = xb;  i = bidx * 256 + tid; }
        else if (bidx < 7168) { src = Wa; dst = Wab; i = (bidx - 4096) * 256 + tid; }
        else                  { src = Wp; dst = Wpb; i = (bidx - 7168) * 256 + tid; }
        float4 v = reinterpret_cast<const float4*>(src)[i];
        ushort4 o;
        o.x = bf_bits(v.x); o.y = bf_bits(v.y); o.z = bf_bits(v.z); o.w = bf_bits(v.w);
        reinterpret_cast<ushort4*>(dst)[i] = o;
    } else {
        int idx = (bidx - 8192) * 256 + tid;    // T_SEQ*32
        int i = idx & 31, tp = idx >> 5;
        float th = (float)tp * freqs[i];
        tab[idx] = make_float2(cosf(th), sinf(th));
    }
}

// ---------------- GEMM: A(M,K) * Bw(N,K)^T, bf16 MFMA ----------------
// BMxBN tile, BK=64, 4 waves (2x2, wave tile (BM/2)x(BN/2)). Single-buffered
// m97 structure; residency set by grid & MINW (r12/r20: residency is the lever).
// MODE 1: bf16 C row-major. MODE 2 (qkv fused epilogue): region = n0>>10:
//   q: RoPE + 0.125*log2e scale -> q_s (B,H,T,D); k: RoPE -> k_s; v: transpose -> v_t.
template<int MODE, int BM, int BN, int MINW>
__global__ __launch_bounds__(256, MINW) void gemm_bt(
    const __hip_bfloat16* __restrict__ A,
    const __hip_bfloat16* __restrict__ Bw,
    void* __restrict__ Cout, int M, int N, int K,
    const float2* __restrict__ tab,
    __hip_bfloat16* __restrict__ q_s,
    __hip_bfloat16* __restrict__ k_s,
    __hip_bfloat16* __restrict__ v_t) {
    constexpr int MF = BM / 32;                   // m-frags per wave
    constexpr int NF = BN / 32;                   // n-frags per wave
    __shared__ __hip_bfloat16 As[BM][64];
    __shared__ __hip_bfloat16 Bs[BN][64];
    const int t = threadIdx.x;
    const int lane = t & 63, w = t >> 6;
    const int wr = w >> 1, wc = w & 1;
    const int l15 = lane & 15, lg = lane >> 4;
    const int m0 = blockIdx.y * BM, n0 = blockIdx.x * BN;

    const int srow = lane >> 3;                   // 0..7 (row within 8-row stripe)
    const int scol = ((lane & 7) ^ srow) * 8;     // pre-swizzled global col granule
    const int xr = (l15 & 7) << 3;                // read-side XOR (element units)

    f32x4 acc[MF][NF];
    f32x4 zero4 = {0.f, 0.f, 0.f, 0.f};
#pragma unroll
    for (int m = 0; m < MF; m++)
#pragma unroll
        for (int n = 0; n < NF; n++) acc[m][n] = zero4;

    const int nt = K >> 6;
    for (int tk = 0; tk < nt; tk++) {
        const int k0 = tk << 6;
#pragma unroll
        for (int i = 0; i < MF; i++) {
            int rbase = w * (BM / 4) + i * 8;
            gload16(&A[(size_t)(m0 + rbase + srow) * K + k0 + scol], &As[rbase][0]);
        }
#pragma unroll
        for (int i = 0; i < NF; i++) {
            int rbase = w * (BN / 4) + i * 8;
            gload16(&Bw[(size_t)(n0 + rbase + srow) * K + k0 + scol], &Bs[rbase][0]);
        }
        __syncthreads();    // drains vmcnt(0): tile ready
#pragma unroll
        for (int kk = 0; kk < 2; kk++) {
            bf16x8 a[MF], b[NF];
            const int co = (kk * 32 + lg * 8) ^ xr;
#pragma unroll
            for (int m = 0; m < MF; m++)
                a[m] = *reinterpret_cast<const bf16x8*>(&As[wr * (BM / 2) + m * 16 + l15][co]);
#pragma unroll
            for (int n = 0; n < NF; n++)
                b[n] = *reinterpret_cast<const bf16x8*>(&Bs[wc * (BN / 2) + n * 16 + l15][co]);
            __builtin_amdgcn_s_setprio(1);
#pragma unroll
            for (int m = 0; m < MF; m++)
#pragma unroll
                for (int n = 0; n < NF; n++)
                    acc[m][n] = __builtin_amdgcn_mfma_f32_16x16x32_bf16(a[m], b[n], acc[m][n], 0, 0, 0);
            __builtin_amdgcn_s_setprio(0);
        }
        __syncthreads();    // all reads done before next stage overwrites
    }

    if (MODE == 2) {
        const int region = n0 >> 10;            // 0=q, 1=k, 2=v (block-uniform)
#pragma unroll
        for (int m = 0; m < MF; m++)
#pragma unroll
            for (int n = 0; n < NF; n++) {
                const int col = n0 + wc * (BN / 2) + n * 16 + l15;
                const int d = col & 63;
                const int h = (col >> 6) & 15;
                const int row0 = m0 + wr * (BM / 2) + m * 16 + lg * 4;
                const int b = row0 >> 11;       // 4 consecutive rows share b (2048|128)
                const int tp0 = row0 & 2047;
                if (region < 2) {
                    const int i = d >> 1, odd = d & 1;
                    const int dp = (d >> 1) + (odd ? 32 : 0);
                    __hip_bfloat16* dst = (region == 0) ? q_s : k_s;
                    const float sc = (region == 0) ? 0.125f * 1.44269504f : 1.0f;
#pragma unroll
                    for (int jj = 0; jj < 4; jj++) {
                        float own = acc[m][n][jj];
                        float par = __shfl_xor(own, 1);
                        float2 cs = tab[(tp0 + jj) * 32 + i];
                        float val = own * cs.x + (odd ? par : -par) * cs.y;
                        dst[((size_t)(b * H_HEADS + h) * T_SEQ + tp0 + jj) * D_HEAD + dp] =
                            __float2bfloat16(val * sc);
                    }
                } else {
                    ushort4 ov;
                    ov.x = bf_bits(acc[m][n][0]);
                    ov.y = bf_bits(acc[m][n][1]);
                    ov.z = bf_bits(acc[m][n][2]);
                    ov.w = bf_bits(acc[m][n][3]);
                    *reinterpret_cast<ushort4*>(
                        &v_t[((size_t)(b * H_HEADS + h) * D_HEAD + d) * T_SEQ + tp0]) = ov;
                }
            }
        return;
    }

#pragma unroll
    for (int m = 0; m < MF; m++)
#pragma unroll
        for (int n = 0; n < NF; n++)
#pragma unroll
            for (int jj = 0; jj < 4; jj++) {
                int row = m0 + wr * (BM / 2) + m * 16 + lg * 4 + jj;
                int col = n0 + wc * (BN / 2) + n * 16 + l15;
                ((__hip_bfloat16*)Cout)[(size_t)row * N + col] = __float2bfloat16(acc[m][n][jj]);
            }
}

// ---------------- flash attention (best measured geometry: 4 waves, 64-row q-tiles) ----
// Block = (head bh, 64-row q tile); 1024 blocks (4 blocks/CU), LPT order.
// Swapped QK^T, in-register P; K/V^T staged via global_load_lds, double-buffered;
// defer-max with shfl-free fast path; MFMA-of-ones row-sum; cvt_pk pack;
// builtin exp2. NOTE: four restructures (512-block pairing r8, 8-wave r14,
// 2-frag r16, direct-global V r18) all regressed — staging doubles as the
// coalescing transform; 16 waves/CU over 4 independent blocks is the optimum.
__global__ __launch_bounds__(256, 4) void attn_kernel(
    const __hip_bfloat16* __restrict__ q_s,
    const __hip_bfloat16* __restrict__ k_s,
    const __hip_bfloat16* __restrict__ v_t,
    __hip_bfloat16* __restrict__ y) {
    __shared__ ushort Kbuf[2][64 * 64];
    __shared__ ushort Vbuf[2][64 * 64];

    const int bid = blockIdx.x;                 // 1024 blocks
    const int qt = 31 - (bid >> 5);             // LPT: longest first
    const int bh = bid & 31;                    // bh%8 -> head-per-XCD L2 locality
    const int t = threadIdx.x, lane = t & 63, w = t >> 6;
    const int l15 = lane & 15, lg = lane >> 4;
    const size_t hbase = (size_t)bh * T_SEQ * D_HEAD;
    const int qr = qt * 64 + w * 16 + l15;

    // Q fragment
    bf16x8 aq[2];
#pragma unroll
    for (int dd = 0; dd < 2; dd++)
        aq[dd] = *reinterpret_cast<const bf16x8*>(&q_s[hbase + (size_t)qr * 64 + dd * 32 + lg * 8]);

    // ones fragment (bf16 1.0 = 0x3F80) for MFMA row-sum
    bf16x8 ones;
#pragma unroll
    for (int i = 0; i < 8; i++) ones[i] = (short)0x3F80;

    f32x4 zero4 = {0.f, 0.f, 0.f, 0.f};
    f32x4 o[4];
#pragma unroll
    for (int dc = 0; dc < 4; dc++) o[dc] = zero4;
    f32x4 lacc = zero4;          // row-sum accumulator ([0] is the live value)
    float mr = -INFINITY;

    // LDS read offsets (element units), hoisted
    int koff[4][2], voff[4][2];
#pragma unroll
    for (int c = 0; c < 4; c++) {
        int kro = ((c >> 1) << 5) + ((c & 1) << 2) + ((l15 >> 2) << 3) + (l15 & 3);
        int sz = swz(kro);
#pragma unroll
        for (int dd = 0; dd < 2; dd++)
            koff[c][dd] = kro * 64 + ((dd * 32 + lg * 8) ^ sz);
    }
#pragma unroll
    for (int dc = 0; dc < 4; dc++) {
        int vro = dc * 16 + l15;
        int sz = swz(vro);
#pragma unroll
        for (int dd = 0; dd < 2; dd++)
            voff[dc][dd] = vro * 64 + ((dd * 32 + lg * 8) ^ sz);
    }

    // staging geometry: thread t -> tile row r_i = i*32 + (t>>3), granule t&7.
    const int srow = t >> 3;                // 0..31
    const int sgr = t & 7;

    auto stageKV = [&](int buf, int kbase) {
#pragma unroll
        for (int i = 0; i < 2; i++) {
            int r = i * 32 + srow;
            int gsw = (sgr ^ (swz(r) >> 3)) * 8;
            gload16(&k_s[hbase + (size_t)(kbase + r) * 64 + gsw],
                    &Kbuf[buf][(i * 32 + w * 8) * 64]);
            gload16(&v_t[hbase + (size_t)r * T_SEQ + kbase + gsw],
                    &Vbuf[buf][(i * 32 + w * 8) * 64]);
        }
    };

    int cur = 0;
    stageKV(0, 0);
    __syncthreads();        // drains vmcnt: buf0 ready

    for (int kt = 0; kt <= qt; kt++) {
        const int kt64 = kt << 6;
        if (kt < qt) stageKV(cur ^ 1, kt64 + 64);   // in flight during compute

        const ushort* Kc = Kbuf[cur];
        const ushort* Vc = Vbuf[cur];
        bf16x8 kf[4][2], av[4][2];
#pragma unroll
        for (int c = 0; c < 4; c++)
#pragma unroll
            for (int dd = 0; dd < 2; dd++)
                kf[c][dd] = *reinterpret_cast<const bf16x8*>(&Kc[koff[c][dd]]);
#pragma unroll
        for (int dc = 0; dc < 4; dc++)
#pragma unroll
            for (int dd = 0; dd < 2; dd++)
                av[dc][dd] = *reinterpret_cast<const bf16x8*>(&Vc[voff[dc][dd]]);

        // ---- S^T = K * Q^T ----
        f32x4 st[4];
        __builtin_amdgcn_s_setprio(1);
#pragma unroll
        for (int c = 0; c < 4; c++) {
            st[c] = zero4;
#pragma unroll
            for (int dd = 0; dd < 2; dd++)
                st[c] = __builtin_amdgcn_mfma_f32_16x16x32_bf16(kf[c][dd], aq[dd], st[c], 0, 0, 0);
        }
        __builtin_amdgcn_s_setprio(0);

        if (kt == qt) {     // causal mask on diagonal tile
#pragma unroll
            for (int c = 0; c < 4; c++) {
                int kb = kt64 + ((c >> 1) << 5) + ((c & 1) << 2) + lg * 8;
#pragma unroll
                for (int jj = 0; jj < 4; jj++)
                    if (kb + jj > qr) st[c][jj] = -INFINITY;
            }
        }

        // ---- per-lane LOCAL max (no cross-lane shuffles on the fast path) ----
        float m0a = fmaxf(st[0][0], st[0][1]), m0b = fmaxf(st[0][2], st[0][3]);
        float m1a = fmaxf(st[1][0], st[1][1]), m1b = fmaxf(st[1][2], st[1][3]);
        float m2a = fmaxf(st[2][0], st[2][1]), m2b = fmaxf(st[2][2], st[2][3]);
        float m3a = fmaxf(st[3][0], st[3][1]), m3b = fmaxf(st[3][2], st[3][3]);
        float lmx = fmaxf(fmaxf(fmaxf(m0a, m0b), fmaxf(m1a, m1b)),
                          fmaxf(fmaxf(m2a, m2b), fmaxf(m3a, m3b)));

        // ---- defer-max: rescale only when some lane's local max grew past THR=8 ----
        if (__any(lmx - mr > 8.f)) {
            float mx = fmaxf(lmx, __shfl_xor(lmx, 16));
            mx = fmaxf(mx, __shfl_xor(mx, 32));
            float mnew = fmaxf(mr, mx);
            float scl = __builtin_amdgcn_exp2f(mr - mnew);
            mr = mnew;
            lacc[0] *= scl;
#pragma unroll
            for (int dc = 0; dc < 4; dc++)
#pragma unroll
                for (int jj = 0; jj < 4; jj++) o[dc][jj] *= scl;
        }

        // ---- P = exp2(S - mr) (bare v_exp_f32), pack to bf16 (cvt_pk) ----
#pragma unroll
        for (int c = 0; c < 4; c++)
#pragma unroll
            for (int jj = 0; jj < 4; jj++)
                st[c][jj] = __builtin_amdgcn_exp2f(st[c][jj] - mr);

        union { bf16x8 v; unsigned int u[4]; } pf0, pf1;
        pf0.u[0] = cvtpk(st[0][0], st[0][1]);
        pf0.u[1] = cvtpk(st[0][2], st[0][3]);
        pf0.u[2] = cvtpk(st[1][0], st[1][1]);
        pf0.u[3] = cvtpk(st[1][2], st[1][3]);
        pf1.u[0] = cvtpk(st[2][0], st[2][1]);
        pf1.u[1] = cvtpk(st[2][2], st[2][3]);
        pf1.u[2] = cvtpk(st[3][0], st[3][1]);
        pf1.u[3] = cvtpk(st[3][2], st[3][3]);

        // ---- O^T += V^T P ; row-sum via MFMA-of-ones ----
        __builtin_amdgcn_s_setprio(1);
        lacc = __builtin_amdgcn_mfma_f32_16x16x32_bf16(ones, pf0.v, lacc, 0, 0, 0);
        lacc = __builtin_amdgcn_mfma_f32_16x16x32_bf16(ones, pf1.v, lacc, 0, 0, 0);
#pragma unroll
        for (int dc = 0; dc < 4; dc++) {
            o[dc] = __builtin_amdgcn_mfma_f32_16x16x32_bf16(av[dc][0], pf0.v, o[dc], 0, 0, 0);
            o[dc] = __builtin_amdgcn_mfma_f32_16x16x32_bf16(av[dc][1], pf1.v, o[dc], 0, 0, 0);
        }
        __builtin_amdgcn_s_setprio(0);

        __syncthreads();    // staged tile ready + all reads of buf[cur] done
        cur ^= 1;
    }

    // epilogue: lane holds o^T[d = dc*16 + lg*4 + jj][q = l15]
    const int b = bh >> 4, h = bh & 15;
    float inv = 1.f / lacc[0];
#pragma unroll
    for (int dc = 0; dc < 4; dc++) {
        ushort4 ov;
        ov.x = bf_bits(o[dc][0] * inv);
        ov.y = bf_bits(o[dc][1] * inv);
        ov.z = bf_bits(o[dc][2] * inv);
        ov.w = bf_bits(o[dc][3] * inv);
        *reinterpret_cast<ushort4*>(
            &y[(size_t)(b * T_SEQ + qr) * C_DIM + h * 64 + dc * 16 + lg * 4]) = ov;
    }
}

// ---------------- LayerNorm over C=1024 (bf16 in, f32 out), one block per row ----------------
__global__ __launch_bounds__(256) void ln_kernel(const __hip_bfloat16* __restrict__ y2,
                                                 const float* __restrict__ wgt,
                                                 const float* __restrict__ bias,
                                                 float* __restrict__ out) {
    const int row = blockIdx.x;
    const int t = threadIdx.x;
    ushort4 u = reinterpret_cast<const ushort4*>(y2 + (size_t)row * C_DIM)[t];
    float4 v;
    v.x = __bfloat162float(*(__hip_bfloat16*)&u.x);
    v.y = __bfloat162float(*(__hip_bfloat16*)&u.y);
    v.z = __bfloat162float(*(__hip_bfloat16*)&u.z);
    v.w = __bfloat162float(*(__hip_bfloat16*)&u.w);
    float s = v.x + v.y + v.z + v.w;
    float s2 = v.x * v.x + v.y * v.y + v.z * v.z + v.w * v.w;
#pragma unroll
    for (int d = 1; d < 64; d <<= 1) {
        s += __shfl_xor(s, d);
        s2 += __shfl_xor(s2, d);
    }
    __shared__ float ps[4], ps2[4];
    const int lane = t & 63, w = t >> 6;
    if (lane == 0) { ps[w] = s; ps2[w] = s2; }
    __syncthreads();
    s = ps[0] + ps[1] + ps[2] + ps[3];
    s2 = ps2[0] + ps2[1] + ps2[2] + ps2[3];
    float mean = s * (1.f / C_DIM);
    float var = s2 * (1.f / C_DIM) - mean * mean;
    float inv = rsqrtf(var + 1e-5f);
    float4 wv = reinterpret_cast<const float4*>(wgt)[t];
    float4 bv = reinterpret_cast<const float4*>(bias)[t];
    float4 ov;
    ov.x = (v.x - mean) * inv * wv.x + bv.x;
    ov.y = (v.y - mean) * inv * wv.y + bv.y;
    ov.z = (v.z - mean) * inv * wv.z + bv.z;
    ov.w = (v.w - mean) * inv * wv.w + bv.w;
    reinterpret_cast<float4*>(out + (size_t)row * C_DIM)[t] = ov;
}

extern "C" void kernel_launch(void* const* d_in, const int* in_sizes, int n_in,
                              void* d_out, int out_size, void* d_ws, size_t ws_size,
                              hipStream_t stream) {
    const float* x      = (const float*)d_in[0];
    const float* freqs  = (const float*)d_in[1];
    const float* W_attn = (const float*)d_in[2];
    const float* W_proj = (const float*)d_in[3];
    const float* lnw    = (const float*)d_in[4];
    const float* lnb    = (const float*)d_in[5];
    float* out = (float*)d_out;
    char* ws = (char*)d_ws;

    __hip_bfloat16* xb   = (__hip_bfloat16*)(ws);                 // 8.4 MB
    __hip_bfloat16* Wab  = (__hip_bfloat16*)(ws + 8388608);       // 6.3 MB
    __hip_bfloat16* Wpb  = (__hip_bfloat16*)(ws + 14680064);      // 2.1 MB
    float2*         tab  = (float2*)(ws + 16777216);              // 512 KB cos/sin table
    __hip_bfloat16* q_s  = (__hip_bfloat16*)(ws + 41943040);      // 8.4 MB
    __hip_bfloat16* k_s  = (__hip_bfloat16*)(ws + 50331648);      // 8.4 MB
    __hip_bfloat16* v_t  = (__hip_bfloat16*)(ws + 58720256);      // 8.4 MB (B,H,D,T)
    __hip_bfloat16* y_at = (__hip_bfloat16*)(ws + 67108864);      // 8.4 MB
    __hip_bfloat16* y2b  = (__hip_bfloat16*)(ws + 75497472);      // 8.4 MB

    // fused casts + rope table (one launch)
    prep_kernel<<<8448, 256, 0, stream>>>(x, W_attn, W_proj, freqs, xb, Wab, Wpb, tab);

    // qkv GEMM with fused RoPE/scatter epilogue: 128x64 tiles, 1536 blocks (~6/CU)
    gemm_bt<2, 128, 64, 5><<<dim3(C3 / 64, BT / 128), 256, 0, stream>>>(
        xb, Wab, nullptr, BT, C3, C_DIM, tab, q_s, k_s, v_t);

    // attention: 1024 blocks (32 q-tiles x 32 heads), LPT order
    attn_kernel<<<1024, 256, 0, stream>>>(q_s, k_s, v_t, y_at);

    // proj: 64x64 tiles, 1024 blocks = 4/CU (bf16 out for cheap LN read)
    gemm_bt<1, 64, 64, 4><<<dim3(C_DIM / 64, BT / 64), 256, 0, stream>>>(
        y_at, Wpb, y2b, BT, C_DIM, C_DIM, nullptr, nullptr, nullptr, nullptr);

    // layernorm
    ln_kernel<<<BT, 256, 0, stream>>>(y2b, lnw, lnb, out);
}

// Round 21
// 104.027 us; speedup vs baseline: 1.0450x; 1.0450x over previous
//
#include <hip/hip_runtime.h>
#include <hip/hip_bf16.h>
#include <math.h>

typedef short bf16x8 __attribute__((ext_vector_type(8)));
typedef float f32x4 __attribute__((ext_vector_type(4)));

#define T_SEQ 2048
#define C_DIM 1024
#define H_HEADS 16
#define D_HEAD 64
#define BT 4096          // B*T
#define C3 3072
#define BH 32            // B*H

static __device__ inline unsigned short bf_bits(float f) {
    __hip_bfloat16 h = __float2bfloat16(f);
    unsigned short u;
    __builtin_memcpy(&u, &h, 2);
    return u;
}

// packed f32x2 -> bf16x2 (RNE), single instruction
static __device__ inline unsigned int cvtpk(float lo, float hi) {
    unsigned int r;
    asm("v_cvt_pk_bf16_f32 %0, %1, %2" : "=v"(r) : "v"(lo), "v"(hi));
    return r;
}

__device__ __forceinline__ void gload16(const void* g, void* l) {
    __builtin_amdgcn_global_load_lds(
        (const __attribute__((address_space(1))) void*)g,
        (__attribute__((address_space(3))) void*)l, 16, 0, 0);
}

// LDS XOR swizzle (element units, 8-elem granule): spreads rows across bank quads
__device__ __forceinline__ int swz(int r) {
    return ((((r & 3) ^ ((r >> 3) & 3)) | (((r >> 3) & 1) << 2)) << 3);
}

// ---------------- fused prep: casts (x, W_attn, W_proj) + RoPE cos/sin table ----------------
__global__ void prep_kernel(const float* __restrict__ x,
                            const float* __restrict__ Wa,
                            const float* __restrict__ Wp,
                            const float* __restrict__ freqs,
                            __hip_bfloat16* __restrict__ xb,
                            __hip_bfloat16* __restrict__ Wab,
                            __hip_bfloat16* __restrict__ Wpb,
                            float2* __restrict__ tab) {
    const int bidx = blockIdx.x, tid = threadIdx.x;
    if (bidx < 8192) {
        const float* src;
        __hip_bfloat16* dst;
        int i;
        if (bidx < 4096)      { src = x;  dst = xb;  i = bidx * 256 + tid; }
        else if (bidx < 7168) { src = Wa; dst = Wab; i = (bidx - 4096) * 256 + tid; }
        else                  { src = Wp; dst = Wpb; i = (bidx - 7168) * 256 + tid; }
        float4 v = reinterpret_cast<const float4*>(src)[i];
        ushort4 o;
        o.x = bf_bits(v.x); o.y = bf_bits(v.y); o.z = bf_bits(v.z); o.w = bf_bits(v.w);
        reinterpret_cast<ushort4*>(dst)[i] = o;
    } else {
        int idx = (bidx - 8192) * 256 + tid;    // T_SEQ*32
        int i = idx & 31, tp = idx >> 5;
        float th = (float)tp * freqs[i];
        tab[idx] = make_float2(cosf(th), sinf(th));
    }
}

// ---------------- GEMM: A(M,K) * Bw(N,K)^T, bf16 MFMA ----------------
// 128xBN tile, BK=64, 4 waves. Single-buffered m97 structure (residency-optimal:
// r11/r12/r20 bracketed the tile space — 128x128 @ 3 blocks/CU is the frontier).
// MODE 1: bf16 C row-major. MODE 2 (qkv fused epilogue): region = n0>>10:
//   q: RoPE + 0.125*log2e scale -> q_s (B,H,T,D); k: RoPE -> k_s; v: transpose -> v_t.
template<int MODE, int BN>
__global__ __launch_bounds__(256) void gemm_bt(
    const __hip_bfloat16* __restrict__ A,
    const __hip_bfloat16* __restrict__ Bw,
    void* __restrict__ Cout, int M, int N, int K,
    const float2* __restrict__ tab,
    __hip_bfloat16* __restrict__ q_s,
    __hip_bfloat16* __restrict__ k_s,
    __hip_bfloat16* __restrict__ v_t) {
    __shared__ __hip_bfloat16 As[128][64];
    __shared__ __hip_bfloat16 Bs[BN][64];
    const int t = threadIdx.x;
    const int lane = t & 63, w = t >> 6;
    const int wr = w >> 1, wc = w & 1;
    const int l15 = lane & 15, lg = lane >> 4;
    const int m0 = blockIdx.y * 128, n0 = blockIdx.x * BN;

    const int srow = lane >> 3;                   // 0..7 (row within 8-row stripe)
    const int scol = ((lane & 7) ^ srow) * 8;     // pre-swizzled global col granule
    const int xr = (l15 & 7) << 3;                // read-side XOR (element units)

    constexpr int NF = BN / 32;                   // n-fragments per wave
    f32x4 acc[4][NF];
    f32x4 zero4 = {0.f, 0.f, 0.f, 0.f};
#pragma unroll
    for (int m = 0; m < 4; m++)
#pragma unroll
        for (int n = 0; n < NF; n++) acc[m][n] = zero4;

    const int nt = K >> 6;
    for (int tk = 0; tk < nt; tk++) {
        const int k0 = tk << 6;
#pragma unroll
        for (int i = 0; i < 4; i++) {
            int rbase = w * 32 + i * 8;
            gload16(&A[(size_t)(m0 + rbase + srow) * K + k0 + scol], &As[rbase][0]);
        }
#pragma unroll
        for (int i = 0; i < NF; i++) {
            int rbase = w * (BN / 4) + i * 8;
            gload16(&Bw[(size_t)(n0 + rbase + srow) * K + k0 + scol], &Bs[rbase][0]);
        }
        __syncthreads();    // drains vmcnt(0): tile ready
#pragma unroll
        for (int kk = 0; kk < 2; kk++) {
            bf16x8 a[4], b[NF];
            const int co = (kk * 32 + lg * 8) ^ xr;
#pragma unroll
            for (int m = 0; m < 4; m++)
                a[m] = *reinterpret_cast<const bf16x8*>(&As[wr * 64 + m * 16 + l15][co]);
#pragma unroll
            for (int n = 0; n < NF; n++)
                b[n] = *reinterpret_cast<const bf16x8*>(&Bs[wc * (BN / 2) + n * 16 + l15][co]);
            __builtin_amdgcn_s_setprio(1);
#pragma unroll
            for (int m = 0; m < 4; m++)
#pragma unroll
                for (int n = 0; n < NF; n++)
                    acc[m][n] = __builtin_amdgcn_mfma_f32_16x16x32_bf16(a[m], b[n], acc[m][n], 0, 0, 0);
            __builtin_amdgcn_s_setprio(0);
        }
        __syncthreads();    // all reads done before next stage overwrites
    }

    if (MODE == 2) {
        const int region = n0 >> 10;            // 0=q, 1=k, 2=v (block-uniform)
#pragma unroll
        for (int m = 0; m < 4; m++)
#pragma unroll
            for (int n = 0; n < NF; n++) {
                const int col = n0 + wc * (BN / 2) + n * 16 + l15;
                const int d = col & 63;
                const int h = (col >> 6) & 15;
                const int row0 = m0 + wr * 64 + m * 16 + lg * 4;
                const int b = row0 >> 11;       // 4 consecutive rows share b (2048|128)
                const int tp0 = row0 & 2047;
                if (region < 2) {
                    const int i = d >> 1, odd = d & 1;
                    const int dp = (d >> 1) + (odd ? 32 : 0);
                    __hip_bfloat16* dst = (region == 0) ? q_s : k_s;
                    const float sc = (region == 0) ? 0.125f * 1.44269504f : 1.0f;
#pragma unroll
                    for (int jj = 0; jj < 4; jj++) {
                        float own = acc[m][n][jj];
                        float par = __shfl_xor(own, 1);
                        float2 cs = tab[(tp0 + jj) * 32 + i];
                        float val = own * cs.x + (odd ? par : -par) * cs.y;
                        dst[((size_t)(b * H_HEADS + h) * T_SEQ + tp0 + jj) * D_HEAD + dp] =
                            __float2bfloat16(val * sc);
                    }
                } else {
                    ushort4 ov;
                    ov.x = bf_bits(acc[m][n][0]);
                    ov.y = bf_bits(acc[m][n][1]);
                    ov.z = bf_bits(acc[m][n][2]);
                    ov.w = bf_bits(acc[m][n][3]);
                    *reinterpret_cast<ushort4*>(
                        &v_t[((size_t)(b * H_HEADS + h) * D_HEAD + d) * T_SEQ + tp0]) = ov;
                }
            }
        return;
    }

#pragma unroll
    for (int m = 0; m < 4; m++)
#pragma unroll
        for (int n = 0; n < NF; n++)
#pragma unroll
            for (int jj = 0; jj < 4; jj++) {
                int row = m0 + wr * 64 + m * 16 + lg * 4 + jj;
                int col = n0 + wc * (BN / 2) + n * 16 + l15;
                ((__hip_bfloat16*)Cout)[(size_t)row * N + col] = __float2bfloat16(acc[m][n][jj]);
            }
}

// ---------------- flash attention (best measured geometry: 4 waves, 64-row q-tiles) ----
// Block = (head bh, 64-row q tile); 1024 blocks (4 blocks/CU), LPT order.
// Swapped QK^T, in-register P; K/V^T staged via global_load_lds, double-buffered;
// defer-max with shfl-free fast path; MFMA-of-ones row-sum; cvt_pk pack;
// builtin exp2. NOTE: four restructures (512-block pairing r8, 8-wave r14,
// 2-frag r16, direct-global V r18) all regressed — staging doubles as the
// coalescing transform; 16 waves/CU over 4 independent blocks is the optimum.
__global__ __launch_bounds__(256, 4) void attn_kernel(
    const __hip_bfloat16* __restrict__ q_s,
    const __hip_bfloat16* __restrict__ k_s,
    const __hip_bfloat16* __restrict__ v_t,
    __hip_bfloat16* __restrict__ y) {
    __shared__ ushort Kbuf[2][64 * 64];
    __shared__ ushort Vbuf[2][64 * 64];

    const int bid = blockIdx.x;                 // 1024 blocks
    const int qt = 31 - (bid >> 5);             // LPT: longest first
    const int bh = bid & 31;                    // bh%8 -> head-per-XCD L2 locality
    const int t = threadIdx.x, lane = t & 63, w = t >> 6;
    const int l15 = lane & 15, lg = lane >> 4;
    const size_t hbase = (size_t)bh * T_SEQ * D_HEAD;
    const int qr = qt * 64 + w * 16 + l15;

    // Q fragment
    bf16x8 aq[2];
#pragma unroll
    for (int dd = 0; dd < 2; dd++)
        aq[dd] = *reinterpret_cast<const bf16x8*>(&q_s[hbase + (size_t)qr * 64 + dd * 32 + lg * 8]);

    // ones fragment (bf16 1.0 = 0x3F80) for MFMA row-sum
    bf16x8 ones;
#pragma unroll
    for (int i = 0; i < 8; i++) ones[i] = (short)0x3F80;

    f32x4 zero4 = {0.f, 0.f, 0.f, 0.f};
    f32x4 o[4];
#pragma unroll
    for (int dc = 0; dc < 4; dc++) o[dc] = zero4;
    f32x4 lacc = zero4;          // row-sum accumulator ([0] is the live value)
    float mr = -INFINITY;

    // LDS read offsets (element units), hoisted
    int koff[4][2], voff[4][2];
#pragma unroll
    for (int c = 0; c < 4; c++) {
        int kro = ((c >> 1) << 5) + ((c & 1) << 2) + ((l15 >> 2) << 3) + (l15 & 3);
        int sz = swz(kro);
#pragma unroll
        for (int dd = 0; dd < 2; dd++)
            koff[c][dd] = kro * 64 + ((dd * 32 + lg * 8) ^ sz);
    }
#pragma unroll
    for (int dc = 0; dc < 4; dc++) {
        int vro = dc * 16 + l15;
        int sz = swz(vro);
#pragma unroll
        for (int dd = 0; dd < 2; dd++)
            voff[dc][dd] = vro * 64 + ((dd * 32 + lg * 8) ^ sz);
    }

    // staging geometry: thread t -> tile row r_i = i*32 + (t>>3), granule t&7.
    const int srow = t >> 3;                // 0..31
    const int sgr = t & 7;

    auto stageKV = [&](int buf, int kbase) {
#pragma unroll
        for (int i = 0; i < 2; i++) {
            int r = i * 32 + srow;
            int gsw = (sgr ^ (swz(r) >> 3)) * 8;
            gload16(&k_s[hbase + (size_t)(kbase + r) * 64 + gsw],
                    &Kbuf[buf][(i * 32 + w * 8) * 64]);
            gload16(&v_t[hbase + (size_t)r * T_SEQ + kbase + gsw],
                    &Vbuf[buf][(i * 32 + w * 8) * 64]);
        }
    };

    int cur = 0;
    stageKV(0, 0);
    __syncthreads();        // drains vmcnt: buf0 ready

    for (int kt = 0; kt <= qt; kt++) {
        const int kt64 = kt << 6;
        if (kt < qt) stageKV(cur ^ 1, kt64 + 64);   // in flight during compute

        const ushort* Kc = Kbuf[cur];
        const ushort* Vc = Vbuf[cur];
        bf16x8 kf[4][2], av[4][2];
#pragma unroll
        for (int c = 0; c < 4; c++)
#pragma unroll
            for (int dd = 0; dd < 2; dd++)
                kf[c][dd] = *reinterpret_cast<const bf16x8*>(&Kc[koff[c][dd]]);
#pragma unroll
        for (int dc = 0; dc < 4; dc++)
#pragma unroll
            for (int dd = 0; dd < 2; dd++)
                av[dc][dd] = *reinterpret_cast<const bf16x8*>(&Vc[voff[dc][dd]]);

        // ---- S^T = K * Q^T ----
        f32x4 st[4];
        __builtin_amdgcn_s_setprio(1);
#pragma unroll
        for (int c = 0; c < 4; c++) {
            st[c] = zero4;
#pragma unroll
            for (int dd = 0; dd < 2; dd++)
                st[c] = __builtin_amdgcn_mfma_f32_16x16x32_bf16(kf[c][dd], aq[dd], st[c], 0, 0, 0);
        }
        __builtin_amdgcn_s_setprio(0);

        if (kt == qt) {     // causal mask on diagonal tile
#pragma unroll
            for (int c = 0; c < 4; c++) {
                int kb = kt64 + ((c >> 1) << 5) + ((c & 1) << 2) + lg * 8;
#pragma unroll
                for (int jj = 0; jj < 4; jj++)
                    if (kb + jj > qr) st[c][jj] = -INFINITY;
            }
        }

        // ---- per-lane LOCAL max (no cross-lane shuffles on the fast path) ----
        float m0a = fmaxf(st[0][0], st[0][1]), m0b = fmaxf(st[0][2], st[0][3]);
        float m1a = fmaxf(st[1][0], st[1][1]), m1b = fmaxf(st[1][2], st[1][3]);
        float m2a = fmaxf(st[2][0], st[2][1]), m2b = fmaxf(st[2][2], st[2][3]);
        float m3a = fmaxf(st[3][0], st[3][1]), m3b = fmaxf(st[3][2], st[3][3]);
        float lmx = fmaxf(fmaxf(fmaxf(m0a, m0b), fmaxf(m1a, m1b)),
                          fmaxf(fmaxf(m2a, m2b), fmaxf(m3a, m3b)));

        // ---- defer-max: rescale only when some lane's local max grew past THR=8 ----
        if (__any(lmx - mr > 8.f)) {
            float mx = fmaxf(lmx, __shfl_xor(lmx, 16));
            mx = fmaxf(mx, __shfl_xor(mx, 32));
            float mnew = fmaxf(mr, mx);
            float scl = __builtin_amdgcn_exp2f(mr - mnew);
            mr = mnew;
            lacc[0] *= scl;
#pragma unroll
            for (int dc = 0; dc < 4; dc++)
#pragma unroll
                for (int jj = 0; jj < 4; jj++) o[dc][jj] *= scl;
        }

        // ---- P = exp2(S - mr) (bare v_exp_f32), pack to bf16 (cvt_pk) ----
#pragma unroll
        for (int c = 0; c < 4; c++)
#pragma unroll
            for (int jj = 0; jj < 4; jj++)
                st[c][jj] = __builtin_amdgcn_exp2f(st[c][jj] - mr);

        union { bf16x8 v; unsigned int u[4]; } pf0, pf1;
        pf0.u[0] = cvtpk(st[0][0], st[0][1]);
        pf0.u[1] = cvtpk(st[0][2], st[0][3]);
        pf0.u[2] = cvtpk(st[1][0], st[1][1]);
        pf0.u[3] = cvtpk(st[1][2], st[1][3]);
        pf1.u[0] = cvtpk(st[2][0], st[2][1]);
        pf1.u[1] = cvtpk(st[2][2], st[2][3]);
        pf1.u[2] = cvtpk(st[3][0], st[3][1]);
        pf1.u[3] = cvtpk(st[3][2], st[3][3]);

        // ---- O^T += V^T P ; row-sum via MFMA-of-ones ----
        __builtin_amdgcn_s_setprio(1);
        lacc = __builtin_amdgcn_mfma_f32_16x16x32_bf16(ones, pf0.v, lacc, 0, 0, 0);
        lacc = __builtin_amdgcn_mfma_f32_16x16x32_bf16(ones, pf1.v, lacc, 0, 0, 0);
#pragma unroll
        for (int dc = 0; dc < 4; dc++) {
            o[dc] = __builtin_amdgcn_mfma_f32_16x16x32_bf16(av[dc][0], pf0.v, o[dc], 0, 0, 0);
            o[dc] = __builtin_amdgcn_mfma_f32_16x16x32_bf16(av[dc][1], pf1.v, o[dc], 0, 0, 0);
        }
        __builtin_amdgcn_s_setprio(0);

        __syncthreads();    // staged tile ready + all reads of buf[cur] done
        cur ^= 1;
    }

    // epilogue: lane holds o^T[d = dc*16 + lg*4 + jj][q = l15]
    const int b = bh >> 4, h = bh & 15;
    float inv = 1.f / lacc[0];
#pragma unroll
    for (int dc = 0; dc < 4; dc++) {
        ushort4 ov;
        ov.x = bf_bits(o[dc][0] * inv);
        ov.y = bf_bits(o[dc][1] * inv);
        ov.z = bf_bits(o[dc][2] * inv);
        ov.w = bf_bits(o[dc][3] * inv);
        *reinterpret_cast<ushort4*>(
            &y[(size_t)(b * T_SEQ + qr) * C_DIM + h * 64 + dc * 16 + lg * 4]) = ov;
    }
}

// ---------------- LayerNorm over C=1024 (bf16 in, f32 out), one block per row ----------------
__global__ __launch_bounds__(256) void ln_kernel(const __hip_bfloat16* __restrict__ y2,
                                                 const float* __restrict__ wgt,
                                                 const float* __restrict__ bias,
                                                 float* __restrict__ out) {
    const int row = blockIdx.x;
    const int t = threadIdx.x;
    ushort4 u = reinterpret_cast<const ushort4*>(y2 + (size_t)row * C_DIM)[t];
    float4 v;
    v.x = __bfloat162float(*(__hip_bfloat16*)&u.x);
    v.y = __bfloat162float(*(__hip_bfloat16*)&u.y);
    v.z = __bfloat162float(*(__hip_bfloat16*)&u.z);
    v.w = __bfloat162float(*(__hip_bfloat16*)&u.w);
    float s = v.x + v.y + v.z + v.w;
    float s2 = v.x * v.x + v.y * v.y + v.z * v.z + v.w * v.w;
#pragma unroll
    for (int d = 1; d < 64; d <<= 1) {
        s += __shfl_xor(s, d);
        s2 += __shfl_xor(s2, d);
    }
    __shared__ float ps[4], ps2[4];
    const int lane = t & 63, w = t >> 6;
    if (lane == 0) { ps[w] = s; ps2[w] = s2; }
    __syncthreads();
    s = ps[0] + ps[1] + ps[2] + ps[3];
    s2 = ps2[0] + ps2[1] + ps2[2] + ps2[3];
    float mean = s * (1.f / C_DIM);
    float var = s2 * (1.f / C_DIM) - mean * mean;
    float inv = rsqrtf(var + 1e-5f);
    float4 wv = reinterpret_cast<const float4*>(wgt)[t];
    float4 bv = reinterpret_cast<const float4*>(bias)[t];
    float4 ov;
    ov.x = (v.x - mean) * inv * wv.x + bv.x;
    ov.y = (v.y - mean) * inv * wv.y + bv.y;
    ov.z = (v.z - mean) * inv * wv.z + bv.z;
    ov.w = (v.w - mean) * inv * wv.w + bv.w;
    reinterpret_cast<float4*>(out + (size_t)row * C_DIM)[t] = ov;
}

extern "C" void kernel_launch(void* const* d_in, const int* in_sizes, int n_in,
                              void* d_out, int out_size, void* d_ws, size_t ws_size,
                              hipStream_t stream) {
    const float* x      = (const float*)d_in[0];
    const float* freqs  = (const float*)d_in[1];
    const float* W_attn = (const float*)d_in[2];
    const float* W_proj = (const float*)d_in[3];
    const float* lnw    = (const float*)d_in[4];
    const float* lnb    = (const float*)d_in[5];
    float* out = (float*)d_out;
    char* ws = (char*)d_ws;

    __hip_bfloat16* xb   = (__hip_bfloat16*)(ws);                 // 8.4 MB
    __hip_bfloat16* Wab  = (__hip_bfloat16*)(ws + 8388608);       // 6.3 MB
    __hip_bfloat16* Wpb  = (__hip_bfloat16*)(ws + 14680064);      // 2.1 MB
    float2*         tab  = (float2*)(ws + 16777216);              // 512 KB cos/sin table
    __hip_bfloat16* q_s  = (__hip_bfloat16*)(ws + 41943040);      // 8.4 MB
    __hip_bfloat16* k_s  = (__hip_bfloat16*)(ws + 50331648);      // 8.4 MB
    __hip_bfloat16* v_t  = (__hip_bfloat16*)(ws + 58720256);      // 8.4 MB (B,H,D,T)
    __hip_bfloat16* y_at = (__hip_bfloat16*)(ws + 67108864);      // 8.4 MB
    __hip_bfloat16* y2b  = (__hip_bfloat16*)(ws + 75497472);      // 8.4 MB

    // fused casts + rope table (one launch)
    prep_kernel<<<8448, 256, 0, stream>>>(x, W_attn, W_proj, freqs, xb, Wab, Wpb, tab);

    // qkv GEMM with fused RoPE/scatter epilogue (no qkv intermediate buffer)
    gemm_bt<2, 128><<<dim3(C3 / 128, BT / 128), 256, 0, stream>>>(
        xb, Wab, nullptr, BT, C3, C_DIM, tab, q_s, k_s, v_t);

    // attention: 1024 blocks (32 q-tiles x 32 heads), LPT order
    attn_kernel<<<1024, 256, 0, stream>>>(q_s, k_s, v_t, y_at);

    // proj (128x64 tile, 512 blocks = 2/CU exactly; bf16 out for cheap LN read)
    gemm_bt<1, 64><<<dim3(C_DIM / 64, BT / 128), 256, 0, stream>>>(
        y_at, Wpb, y2b, BT, C_DIM, C_DIM, nullptr, nullptr, nullptr, nullptr);

    // layernorm
    ln_kernel<<<BT, 256, 0, stream>>>(y2b, lnw, lnb, out);
}